// Round 1
// 230.505 us; speedup vs baseline: 1.0082x; 1.0082x over previous
//
#include <hip/hip_runtime.h>
#include <hip/hip_bf16.h>
#include <math.h>

#define Bb 4
#define Nn 2048
#define Ee 768
#define Hh 12
#define Dd 64
#define RD 32
#define EPSf 1e-6f
#define NEG_BIG -3.0e38f
#define NTQ 32   // number of 64-row q tiles per (b,h)

typedef __attribute__((ext_vector_type(8))) short short8;
typedef __attribute__((ext_vector_type(4))) float f32x4;

__device__ inline float wave_reduce_sum(float v) {
    #pragma unroll
    for (int m = 1; m < 64; m <<= 1) v += __shfl_xor(v, m, 64);
    return v;
}

// scalar round-to-nearest-even fp32 -> bf16 bits (cheap kernels only)
__device__ inline unsigned f2bf(float x) {
    union { float f; unsigned u; } c; c.f = x;
    unsigned r = c.u + 0x7FFFu + ((c.u >> 16) & 1u);
    return r >> 16;
}

// packed fp32x2 -> bf16x2 (v_cvt_pk_bf16_f32)
__device__ inline unsigned pk_bf16(float a, float b) {
    union { __hip_bfloat162 h; unsigned u; } c;
    c.h = __float22bfloat162_rn(float2{a, b});
    return c.u;
}

// async global->LDS DMA, 16 B per lane; lds dest = uniform base + lane*16
__device__ inline void gload16(const void* g, void* l) {
    __builtin_amdgcn_global_load_lds(
        (const __attribute__((address_space(1))) void*)g,
        (__attribute__((address_space(3))) void*)l,
        16, 0, 0);
}

// Fused: rope/xpos tables (fp64) + W fp32->bf16 conversion.
// Blocks [0, 128): tables; blocks [128, 128+576): W convert.
__global__ __launch_bounds__(256) void misc_kernel(
    float* __restrict__ ctab, float* __restrict__ stab, float* __restrict__ sctab,
    const float* __restrict__ w, unsigned short* __restrict__ wb)
{
    int bx = blockIdx.x;
    if (bx < 128) {
        int idx = bx * 256 + threadIdx.x;
        int n = idx >> 4, i = idx & 15;
        double inv_freq = pow(10000.0, -(double)(2 * i) / (double)RD);
        double ang = (double)n * inv_freq;
        ctab[idx] = (float)cos(ang);
        stab[idx] = (float)sin(ang);
        double base = (2.0 * (double)i + 0.4 * (double)RD) / (1.4 * (double)RD);
        double pw = ((double)n - (double)(Nn / 2)) / 512.0;
        sctab[idx] = (float)pow(base, pw);
    } else {
        int idx = (bx - 128) * 256 + threadIdx.x;   // one float4 each
        float4 v = ((const float4*)w)[idx];
        uint2 uu;
        uu.x = pk_bf16(v.x, v.y);
        uu.y = pk_bf16(v.z, v.w);
        *(uint2*)(wb + (size_t)idx * 4) = uu;
    }
}

// One wave per (b,h,n): RMS-norm + xPos rope; writes bf16 (B,H,N,D).
// 1/sqrt(D) * log2(e) folded into q so softmax uses exp2.
__global__ __launch_bounds__(256) void prep_kernel(
    const float* __restrict__ q, const float* __restrict__ k,
    const float* __restrict__ qscale, const float* __restrict__ kscale,
    const float* __restrict__ ctab, const float* __restrict__ stab,
    const float* __restrict__ sctab,
    unsigned short* __restrict__ qn, unsigned short* __restrict__ kn)
{
    int wave = blockIdx.x * 4 + (threadIdx.x >> 6);
    int lane = threadIdx.x & 63;
    int n  = wave % Nn;
    int bh = wave / Nn;
    int h  = bh % Hh;
    int b  = bh / Hh;
    int gidx = (b * Nn + n) * Ee + h * Dd + lane;
    float xq = q[gidx], xk = k[gidx];
    float msq = wave_reduce_sum(xq * xq) * (1.0f / 64.0f);
    float msk = wave_reduce_sum(xk * xk) * (1.0f / 64.0f);
    float xqn = xq * qscale[lane] * rsqrtf(msq + EPSf);
    float xkn = xk * kscale[lane] * rsqrtf(msk + EPSf);
    float pq = __shfl_xor(xqn, 1, 64);
    float pk = __shfl_xor(xkn, 1, 64);
    float oq = xqn, ok = xkn;
    if (lane < RD) {
        int i = lane >> 1;
        float c  = ctab[n * 16 + i];
        float s  = stab[n * 16 + i];
        float sc = sctab[n * 16 + i];
        float rq = (lane & 1) ? pq : -pq;
        float rk = (lane & 1) ? pk : -pk;
        oq = (xqn * c + rq * s) * sc;
        ok = (xkn * c + rk * s) / sc;
    }
    oq *= 0.125f * 1.44269504088896f;   // 1/sqrt(D) * log2(e)
    size_t oidx = (size_t)bh * (Nn * Dd) + (size_t)n * Dd + lane;
    qn[oidx] = (unsigned short)f2bf(oq);
    kn[oidx] = (unsigned short)f2bf(ok);
}

// Transpose V: (B,N,E) fp32 -> (B,H,D,N) bf16
__global__ __launch_bounds__(256) void vt_kernel(
    const float* __restrict__ v, unsigned short* __restrict__ vt)
{
    __shared__ float Vl[64 * 65];
    int t = threadIdx.x;
    int bh = blockIdx.x >> 5;
    int n0 = (blockIdx.x & 31) * 64;
    int b = bh / Hh, h = bh % Hh;
    const float4* v4 = (const float4*)v;
    #pragma unroll
    for (int c = 0; c < 4; ++c) {
        int idx = t + c * 256;
        int n = idx >> 4, d4 = idx & 15;
        float4 vv = v4[(size_t)(b * Nn + n0 + n) * (Ee / 4) + h * 16 + d4];
        int la = n * 65 + d4 * 4;
        Vl[la] = vv.x; Vl[la + 1] = vv.y; Vl[la + 2] = vv.z; Vl[la + 3] = vv.w;
    }
    __syncthreads();
    #pragma unroll
    for (int c = 0; c < 16; ++c) {
        int linear = t + c * 256;
        int d = linear >> 6, n = linear & 63;
        vt[((size_t)bh * Dd + d) * Nn + n0 + n] = (unsigned short)f2bf(Vl[n * 65 + d]);
    }
}

// MFMA flash attention (causal).
// Single q-tile per block, heavy-first dispatch (qt = 31 - blockIdx.y).
// Double-buffered K/V staging: ONE barrier per tile; DMA of tile t+1 in
// flight under tile t's compute (m97/T3-minimum structure).
// LDS = 16K (K x2) + 16K (V x2) + 8K (P) = 40960 B -> 4 blocks/CU.
// grid (48, 32): blockIdx.x = bh so linear%8 = bh%8 -> per-XCD K/V locality.
__global__ __launch_bounds__(256) void attn_kernel(
    const unsigned short* __restrict__ qn, const unsigned short* __restrict__ kn,
    const unsigned short* __restrict__ vt, unsigned short* __restrict__ y)
{
    __shared__ __align__(16) unsigned short Kl[2][64 * 64];
    __shared__ __align__(16) unsigned short Vl[2][64 * 64];    // V^T: [dim][key]
    __shared__ __align__(16) unsigned short Pl[4 * 16 * 64];   // pitch 64 + chunk-XOR
    int t = threadIdx.x;
    int w = t >> 6, lane = t & 63;
    int quad = lane >> 4, col = lane & 15;
    int bh = blockIdx.x;
    int b = bh / Hh, h = bh % Hh;
    int qt = (NTQ - 1) - (int)blockIdx.y;      // heavy blocks dispatched first
    const unsigned short* kbh = kn + (size_t)bh * Nn * Dd;
    const unsigned short* vbh = vt + (size_t)bh * Dd * Nn;
    unsigned short* Plw = Pl + w * 16 * 64;

    int l8 = lane >> 3, c8 = lane & 7;
    int g8 = (c8 ^ l8) * 8;                 // element offset of source chunk
    int sw = col & 7;
    int i0 = ((quad    ) ^ sw) * 8;         // chunks 0..31
    int i1 = ((quad + 4) ^ sw) * 8;         // chunks 32..63

    int q0 = qt * 64;
    int qrow = q0 + w * 16 + col;
    const unsigned short* qp = qn + ((size_t)bh * Nn + qrow) * Dd;
    short8 qf0 = *(const short8*)(qp + quad * 8);
    short8 qf1 = *(const short8*)(qp + 32 + quad * 8);

    f32x4 O[4];
    #pragma unroll
    for (int i = 0; i < 4; ++i) O[i] = (f32x4){0.f, 0.f, 0.f, 0.f};
    float m = NEG_BIG, l = 0.0f;
    int ntiles = qt + 1;

    // prologue: stage tile 0 into buffer 0
    #pragma unroll
    for (int c = 0; c < 2; ++c) {
        int r = w * 16 + c * 8 + l8;
        int dstbase = (w * 16 + c * 8) * 64;
        gload16(kbh + ((size_t)r << 6) + g8, &Kl[0][dstbase]);
        gload16(vbh + (size_t)r * Nn + g8, &Vl[0][dstbase]);
    }

    for (int tile = 0; tile < ntiles; ++tile) {
        int cur = tile & 1;
        int j0 = tile * 64;
        // drain my DMA for buffer[cur]; barrier makes all waves' stages
        // visible AND guarantees buffer[cur^1] readers (tile-1) are done.
        asm volatile("s_waitcnt vmcnt(0)" ::: "memory");
        __syncthreads();
        if (tile + 1 < ntiles) {           // prefetch next tile -> other buffer
            int j0n = j0 + 64;
            #pragma unroll
            for (int c = 0; c < 2; ++c) {
                int r = w * 16 + c * 8 + l8;
                int dstbase = (w * 16 + c * 8) * 64;
                gload16(kbh + ((size_t)(j0n + r) << 6) + g8, &Kl[cur ^ 1][dstbase]);
                gload16(vbh + (size_t)r * Nn + j0n + g8, &Vl[cur ^ 1][dstbase]);
            }
        }

        // S^T = K . Q^T
        f32x4 S[4];
        #pragma unroll
        for (int i = 0; i < 4; ++i) S[i] = (f32x4){0.f, 0.f, 0.f, 0.f};
        __builtin_amdgcn_s_setprio(1);
        #pragma unroll
        for (int mt = 0; mt < 4; ++mt) {
            const unsigned short* rowp = &Kl[cur][(col + 16 * mt) * 64];
            short8 a0 = *(const short8*)(rowp + i0);
            S[mt] = __builtin_amdgcn_mfma_f32_16x16x32_bf16(a0, qf0, S[mt], 0, 0, 0);
            short8 a1 = *(const short8*)(rowp + i1);
            S[mt] = __builtin_amdgcn_mfma_f32_16x16x32_bf16(a1, qf1, S[mt], 0, 0, 0);
        }
        __builtin_amdgcn_s_setprio(0);
        if (j0 + 63 > q0 + w * 16) {   // diagonal tile: causal mask
            #pragma unroll
            for (int mt = 0; mt < 4; ++mt)
                #pragma unroll
                for (int r = 0; r < 4; ++r) {
                    int key = j0 + mt * 16 + quad * 4 + r;
                    if (key > qrow) S[mt][r] = NEG_BIG;
                }
        }
        // online softmax (base-2; log2e folded into q)
        float rmax = S[0][0];
        #pragma unroll
        for (int mt = 0; mt < 4; ++mt)
            #pragma unroll
            for (int r = 0; r < 4; ++r) rmax = fmaxf(rmax, S[mt][r]);
        rmax = fmaxf(rmax, __shfl_xor(rmax, 16, 64));
        rmax = fmaxf(rmax, __shfl_xor(rmax, 32, 64));
        // defer-rescale: if no lane raised its row max, alpha == 1 exactly.
        if (!__all(rmax <= m)) {
            float mn = fmaxf(m, rmax);
            float alpha = exp2f(m - mn);
            l *= alpha;
            #pragma unroll
            for (int i = 0; i < 4; ++i) O[i] *= alpha;
            m = mn;
        }
        float P[4][4];
        float rsum = 0.0f;
        #pragma unroll
        for (int mt = 0; mt < 4; ++mt)
            #pragma unroll
            for (int r = 0; r < 4; ++r) {
                P[mt][r] = exp2f(S[mt][r] - m);
                rsum += P[mt][r];
            }
        rsum += __shfl_xor(rsum, 16, 64);
        rsum += __shfl_xor(rsum, 32, 64);
        l += rsum;
        // pack P -> LDS (pitch 64 shorts, 16B-chunk XOR swizzle by col&7)
        #pragma unroll
        for (int mt = 0; mt < 4; ++mt) {
            uint2 uu;
            uu.x = pk_bf16(P[mt][0], P[mt][1]);
            uu.y = pk_bf16(P[mt][2], P[mt][3]);
            int pidx = col * 64 + (((2 * mt + (quad >> 1)) ^ sw) << 3) + ((quad & 1) << 2);
            *(uint2*)(Plw + pidx) = uu;
        }
        asm volatile("s_waitcnt lgkmcnt(0)" ::: "memory");
        short8 pf0 = *(const short8*)(Plw + col * 64 + ((quad ^ sw) << 3));
        short8 pf1 = *(const short8*)(Plw + col * 64 + (((quad + 4) ^ sw) << 3));
        // O^T += V^T . P^T
        __builtin_amdgcn_s_setprio(1);
        #pragma unroll
        for (int mt = 0; mt < 4; ++mt) {
            const unsigned short* rowp = &Vl[cur][(col + 16 * mt) * 64];
            short8 a0 = *(const short8*)(rowp + i0);
            O[mt] = __builtin_amdgcn_mfma_f32_16x16x32_bf16(a0, pf0, O[mt], 0, 0, 0);
            short8 a1 = *(const short8*)(rowp + i1);
            O[mt] = __builtin_amdgcn_mfma_f32_16x16x32_bf16(a1, pf1, O[mt], 0, 0, 0);
        }
        __builtin_amdgcn_s_setprio(0);
    }
    float rl = 1.0f / l;
    unsigned short* yp = y + ((size_t)b * Nn + qrow) * Ee + h * Dd;
    #pragma unroll
    for (int mt = 0; mt < 4; ++mt) {
        f32x4 o = O[mt] * rl;
        uint2 uu;
        uu.x = pk_bf16(o[0], o[1]);
        uu.y = pk_bf16(o[2], o[3]);
        *(uint2*)(yp + mt * 16 + quad * 4) = uu;
    }
}

// MFMA NT GEMM: out[m][e] = sum_f y[m][f]*W[e][f] + bias[e]
// 64(m) x 128(e) tile, BK=64, async-DMA + XOR swizzle staging, grid (6,128).
// Wave wv owns e-range wv*32: acc[mi 0..3][ni 0..1].
__global__ __launch_bounds__(256) void proj_kernel(
    const unsigned short* __restrict__ y, const unsigned short* __restrict__ w,
    const float* __restrict__ bias, float* __restrict__ out)
{
    __shared__ __align__(16) unsigned short Al[64 * 64];
    __shared__ __align__(16) unsigned short Bl[128 * 64];
    int t = threadIdx.x;
    int wv = t >> 6, lane = t & 63;
    int quad = lane >> 4, col = lane & 15;
    int e0 = blockIdx.x * 128, m0 = blockIdx.y * 64;
    int l8 = lane >> 3, c8 = lane & 7;
    int g8 = (c8 ^ l8) * 8;
    f32x4 acc[4][2];
    #pragma unroll
    for (int i = 0; i < 4; ++i)
        #pragma unroll
        for (int j = 0; j < 2; ++j) acc[i][j] = (f32x4){0.f, 0.f, 0.f, 0.f};

    for (int k0 = 0; k0 < Ee; k0 += 64) {
        __syncthreads();
        // A: 64 rows (m); wave wv feeds rows wv*16 .. +15
        #pragma unroll
        for (int c = 0; c < 2; ++c) {
            int r = wv * 16 + c * 8 + l8;
            gload16(y + (size_t)(m0 + r) * Ee + k0 + g8, Al + (wv * 16 + c * 8) * 64);
        }
        // B: 128 rows (e); wave wv feeds rows wv*32 .. +31
        #pragma unroll
        for (int c = 0; c < 4; ++c) {
            int r = wv * 32 + c * 8 + l8;
            gload16(w + (size_t)(e0 + r) * Ee + k0 + g8, Bl + (wv * 32 + c * 8) * 64);
        }
        __syncthreads();
        #pragma unroll
        for (int kc = 0; kc < 2; ++kc) {
            short8 a[4], bb[2];
            #pragma unroll
            for (int mi = 0; mi < 4; ++mi) {
                int row = mi * 16 + col;
                int sl = ((kc * 4 + quad) ^ (row & 7)) * 8;
                a[mi] = *(const short8*)(Al + row * 64 + sl);
            }
            #pragma unroll
            for (int ni = 0; ni < 2; ++ni) {
                int row = wv * 32 + ni * 16 + col;
                int sl = ((kc * 4 + quad) ^ (row & 7)) * 8;
                bb[ni] = *(const short8*)(Bl + row * 64 + sl);
            }
            #pragma unroll
            for (int mi = 0; mi < 4; ++mi)
                #pragma unroll
                for (int ni = 0; ni < 2; ++ni)
                    acc[mi][ni] = __builtin_amdgcn_mfma_f32_16x16x32_bf16(a[mi], bb[ni], acc[mi][ni], 0, 0, 0);
        }
    }
    // C layout: e-col = col, m-row = quad*4 + r
    #pragma unroll
    for (int ni = 0; ni < 2; ++ni) {
        int e = e0 + wv * 32 + ni * 16 + col;
        float be = bias[e];
        #pragma unroll
        for (int mi = 0; mi < 4; ++mi) {
            int mrow = m0 + mi * 16 + quad * 4;
            #pragma unroll
            for (int r = 0; r < 4; ++r)
                out[(size_t)(mrow + r) * Ee + e] = acc[mi][ni][r] + be;
        }
    }
}

extern "C" void kernel_launch(void* const* d_in, const int* in_sizes, int n_in,
                              void* d_out, int out_size, void* d_ws, size_t ws_size,
                              hipStream_t stream) {
    const float* q      = (const float*)d_in[0];
    const float* k      = (const float*)d_in[1];
    const float* v      = (const float*)d_in[2];
    const float* qscale = (const float*)d_in[3];
    const float* kscale = (const float*)d_in[4];
    const float* projw  = (const float*)d_in[5];
    const float* projb  = (const float*)d_in[6];
    float* out = (float*)d_out;

    char* base = (char*)d_ws;
    float* ctab  = (float*)(base);
    float* stab  = (float*)(base + 131072);
    float* sctab = (float*)(base + 262144);
    unsigned short* qn   = (unsigned short*)(base + 393216);
    unsigned short* kn   = (unsigned short*)(base + 12976128);
    unsigned short* vt   = (unsigned short*)(base + 25559040);
    unsigned short* yatt = (unsigned short*)(base + 38141952);
    unsigned short* wb   = (unsigned short*)(base + 50724864);

    misc_kernel<<<128 + (Ee * Ee / 4) / 256, 256, 0, stream>>>(
        ctab, stab, sctab, projw, wb);
    prep_kernel<<<(Bb * Hh * Nn) / 4, 256, 0, stream>>>(
        q, k, qscale, kscale, ctab, stab, sctab, qn, kn);
    vt_kernel<<<Bb * Hh * 32, 256, 0, stream>>>(v, vt);

    dim3 agrid(Bb * Hh, NTQ);                            // (48, 32): bh -> XCD
    attn_kernel<<<agrid, 256, 0, stream>>>(qn, kn, vt, yatt);

    dim3 ggrid(Ee / 128, (Bb * Nn) / 64);                // (6, 128)
    proj_kernel<<<ggrid, 256, 0, stream>>>(yatt, wb, projb, out);
}

// Round 2
// 220.101 us; speedup vs baseline: 1.0558x; 1.0473x over previous
//
#include <hip/hip_runtime.h>
#include <hip/hip_bf16.h>
#include <math.h>

#define Bb 4
#define Nn 2048
#define Ee 768
#define Hh 12
#define Dd 64
#define RD 32
#define EPSf 1e-6f
#define NEG_BIG -3.0e38f
#define NTQ 32   // number of 64-row q tiles per (b,h)

typedef __attribute__((ext_vector_type(8))) short short8;
typedef __attribute__((ext_vector_type(4))) float f32x4;

__device__ inline float wave_reduce_sum(float v) {
    #pragma unroll
    for (int m = 1; m < 64; m <<= 1) v += __shfl_xor(v, m, 64);
    return v;
}

// scalar round-to-nearest-even fp32 -> bf16 bits (cheap kernels only)
__device__ inline unsigned f2bf(float x) {
    union { float f; unsigned u; } c; c.f = x;
    unsigned r = c.u + 0x7FFFu + ((c.u >> 16) & 1u);
    return r >> 16;
}

// packed fp32x2 -> bf16x2 (v_cvt_pk_bf16_f32)
__device__ inline unsigned pk_bf16(float a, float b) {
    union { __hip_bfloat162 h; unsigned u; } c;
    c.h = __float22bfloat162_rn(float2{a, b});
    return c.u;
}

// async global->LDS DMA, 16 B per lane; lds dest = uniform base + lane*16
__device__ inline void gload16(const void* g, void* l) {
    __builtin_amdgcn_global_load_lds(
        (const __attribute__((address_space(1))) void*)g,
        (__attribute__((address_space(3))) void*)l,
        16, 0, 0);
}

// Fused: rope/xpos tables (fp64) + W fp32->bf16 conversion.
// Blocks [0, 128): tables; blocks [128, 128+576): W convert.
__global__ __launch_bounds__(256) void misc_kernel(
    float* __restrict__ ctab, float* __restrict__ stab, float* __restrict__ sctab,
    const float* __restrict__ w, unsigned short* __restrict__ wb)
{
    int bx = blockIdx.x;
    if (bx < 128) {
        int idx = bx * 256 + threadIdx.x;
        int n = idx >> 4, i = idx & 15;
        double inv_freq = pow(10000.0, -(double)(2 * i) / (double)RD);
        double ang = (double)n * inv_freq;
        ctab[idx] = (float)cos(ang);
        stab[idx] = (float)sin(ang);
        double base = (2.0 * (double)i + 0.4 * (double)RD) / (1.4 * (double)RD);
        double pw = ((double)n - (double)(Nn / 2)) / 512.0;
        sctab[idx] = (float)pow(base, pw);
    } else {
        int idx = (bx - 128) * 256 + threadIdx.x;   // one float4 each
        float4 v = ((const float4*)w)[idx];
        uint2 uu;
        uu.x = pk_bf16(v.x, v.y);
        uu.y = pk_bf16(v.z, v.w);
        *(uint2*)(wb + (size_t)idx * 4) = uu;
    }
}

// One wave per (b,h,n): RMS-norm + xPos rope; writes bf16 (B,H,N,D).
// 1/sqrt(D) * log2(e) folded into q so softmax uses exp2.
__global__ __launch_bounds__(256) void prep_kernel(
    const float* __restrict__ q, const float* __restrict__ k,
    const float* __restrict__ qscale, const float* __restrict__ kscale,
    const float* __restrict__ ctab, const float* __restrict__ stab,
    const float* __restrict__ sctab,
    unsigned short* __restrict__ qn, unsigned short* __restrict__ kn)
{
    int wave = blockIdx.x * 4 + (threadIdx.x >> 6);
    int lane = threadIdx.x & 63;
    int n  = wave % Nn;
    int bh = wave / Nn;
    int h  = bh % Hh;
    int b  = bh / Hh;
    int gidx = (b * Nn + n) * Ee + h * Dd + lane;
    float xq = q[gidx], xk = k[gidx];
    float msq = wave_reduce_sum(xq * xq) * (1.0f / 64.0f);
    float msk = wave_reduce_sum(xk * xk) * (1.0f / 64.0f);
    float xqn = xq * qscale[lane] * rsqrtf(msq + EPSf);
    float xkn = xk * kscale[lane] * rsqrtf(msk + EPSf);
    float pq = __shfl_xor(xqn, 1, 64);
    float pk = __shfl_xor(xkn, 1, 64);
    float oq = xqn, ok = xkn;
    if (lane < RD) {
        int i = lane >> 1;
        float c  = ctab[n * 16 + i];
        float s  = stab[n * 16 + i];
        float sc = sctab[n * 16 + i];
        float rq = (lane & 1) ? pq : -pq;
        float rk = (lane & 1) ? pk : -pk;
        oq = (xqn * c + rq * s) * sc;
        ok = (xkn * c + rk * s) / sc;
    }
    oq *= 0.125f * 1.44269504088896f;   // 1/sqrt(D) * log2(e)
    size_t oidx = (size_t)bh * (Nn * Dd) + (size_t)n * Dd + lane;
    qn[oidx] = (unsigned short)f2bf(oq);
    kn[oidx] = (unsigned short)f2bf(ok);
}

// Transpose V: (B,N,E) fp32 -> (B,H,D,N) bf16
__global__ __launch_bounds__(256) void vt_kernel(
    const float* __restrict__ v, unsigned short* __restrict__ vt)
{
    __shared__ float Vl[64 * 65];
    int t = threadIdx.x;
    int bh = blockIdx.x >> 5;
    int n0 = (blockIdx.x & 31) * 64;
    int b = bh / Hh, h = bh % Hh;
    const float4* v4 = (const float4*)v;
    #pragma unroll
    for (int c = 0; c < 4; ++c) {
        int idx = t + c * 256;
        int n = idx >> 4, d4 = idx & 15;
        float4 vv = v4[(size_t)(b * Nn + n0 + n) * (Ee / 4) + h * 16 + d4];
        int la = n * 65 + d4 * 4;
        Vl[la] = vv.x; Vl[la + 1] = vv.y; Vl[la + 2] = vv.z; Vl[la + 3] = vv.w;
    }
    __syncthreads();
    #pragma unroll
    for (int c = 0; c < 16; ++c) {
        int linear = t + c * 256;
        int d = linear >> 6, n = linear & 63;
        vt[((size_t)bh * Dd + d) * Nn + n0 + n] = (unsigned short)f2bf(Vl[n * 65 + d]);
    }
}

// MFMA flash attention (causal), NO-MAX softmax.
// |S*log2e/8| <= ~13.5 (rms-norm + xPos decay bound), so exp2(S) is safe in
// fp32/bf16 without max subtraction: P = exp2(S), l = sum(P) per-lane partial,
// one cross-lane reduce after the loop, normalize by 1/l at the end.
// Double-buffered K/V staging, one barrier per tile, heavy-first dispatch.
// LDS = 16K (K x2) + 16K (V x2) + 8K (P) = 40960 B -> 4 blocks/CU.
__global__ __launch_bounds__(256) void attn_kernel(
    const unsigned short* __restrict__ qn, const unsigned short* __restrict__ kn,
    const unsigned short* __restrict__ vt, unsigned short* __restrict__ y)
{
    __shared__ __align__(16) unsigned short Kl[2][64 * 64];
    __shared__ __align__(16) unsigned short Vl[2][64 * 64];    // V^T: [dim][key]
    __shared__ __align__(16) unsigned short Pl[4 * 16 * 64];   // pitch 64 + chunk-XOR
    int t = threadIdx.x;
    int w = t >> 6, lane = t & 63;
    int quad = lane >> 4, col = lane & 15;
    int bh = blockIdx.x;
    int b = bh / Hh, h = bh % Hh;
    int qt = (NTQ - 1) - (int)blockIdx.y;      // heavy blocks dispatched first
    const unsigned short* kbh = kn + (size_t)bh * Nn * Dd;
    const unsigned short* vbh = vt + (size_t)bh * Dd * Nn;
    unsigned short* Plw = Pl + w * 16 * 64;

    int l8 = lane >> 3, c8 = lane & 7;
    int g8 = (c8 ^ l8) * 8;                 // element offset of source chunk
    int sw = col & 7;
    int i0 = ((quad    ) ^ sw) * 8;         // chunks 0..31
    int i1 = ((quad + 4) ^ sw) * 8;         // chunks 32..63

    int q0 = qt * 64;
    int qrow = q0 + w * 16 + col;
    const unsigned short* qp = qn + ((size_t)bh * Nn + qrow) * Dd;
    short8 qf0 = *(const short8*)(qp + quad * 8);
    short8 qf1 = *(const short8*)(qp + 32 + quad * 8);

    const f32x4 Zc = (f32x4){0.f, 0.f, 0.f, 0.f};   // loop-invariant zero C
    f32x4 O[4];
    #pragma unroll
    for (int i = 0; i < 4; ++i) O[i] = Zc;
    float l = 0.0f;                                  // per-lane partial sum
    int ntiles = qt + 1;

    // prologue: stage tile 0 into buffer 0
    #pragma unroll
    for (int c = 0; c < 2; ++c) {
        int r = w * 16 + c * 8 + l8;
        int dstbase = (w * 16 + c * 8) * 64;
        gload16(kbh + ((size_t)r << 6) + g8, &Kl[0][dstbase]);
        gload16(vbh + (size_t)r * Nn + g8, &Vl[0][dstbase]);
    }

    for (int tile = 0; tile < ntiles; ++tile) {
        int cur = tile & 1;
        int j0 = tile * 64;
        // drain my DMA for buffer[cur]; barrier makes all waves' stages
        // visible AND guarantees buffer[cur^1] readers (tile-1) are done.
        asm volatile("s_waitcnt vmcnt(0)" ::: "memory");
        __syncthreads();
        if (tile + 1 < ntiles) {           // prefetch next tile -> other buffer
            int j0n = j0 + 64;
            #pragma unroll
            for (int c = 0; c < 2; ++c) {
                int r = w * 16 + c * 8 + l8;
                int dstbase = (w * 16 + c * 8) * 64;
                gload16(kbh + ((size_t)(j0n + r) << 6) + g8, &Kl[cur ^ 1][dstbase]);
                gload16(vbh + (size_t)r * Nn + j0n + g8, &Vl[cur ^ 1][dstbase]);
            }
        }

        // S^T = K . Q^T  (C-in = loop-invariant zero: no per-tile S init)
        f32x4 S[4];
        __builtin_amdgcn_s_setprio(1);
        #pragma unroll
        for (int mt = 0; mt < 4; ++mt) {
            const unsigned short* rowp = &Kl[cur][(col + 16 * mt) * 64];
            short8 a0 = *(const short8*)(rowp + i0);
            S[mt] = __builtin_amdgcn_mfma_f32_16x16x32_bf16(a0, qf0, Zc, 0, 0, 0);
            short8 a1 = *(const short8*)(rowp + i1);
            S[mt] = __builtin_amdgcn_mfma_f32_16x16x32_bf16(a1, qf1, S[mt], 0, 0, 0);
        }
        __builtin_amdgcn_s_setprio(0);
        if (j0 + 63 > q0 + w * 16) {   // diagonal tile: causal mask
            #pragma unroll
            for (int mt = 0; mt < 4; ++mt)
                #pragma unroll
                for (int r = 0; r < 4; ++r) {
                    int key = j0 + mt * 16 + quad * 4 + r;
                    if (key > qrow) S[mt][r] = NEG_BIG;
                }
        }
        // no-max softmax: P = exp2(S) directly (bounded), accumulate lane-local l
        float P[4][4];
        #pragma unroll
        for (int mt = 0; mt < 4; ++mt)
            #pragma unroll
            for (int r = 0; r < 4; ++r) {
                P[mt][r] = exp2f(S[mt][r]);
                l += P[mt][r];
            }
        // pack P -> LDS (pitch 64 shorts, 16B-chunk XOR swizzle by col&7)
        #pragma unroll
        for (int mt = 0; mt < 4; ++mt) {
            uint2 uu;
            uu.x = pk_bf16(P[mt][0], P[mt][1]);
            uu.y = pk_bf16(P[mt][2], P[mt][3]);
            int pidx = col * 64 + (((2 * mt + (quad >> 1)) ^ sw) << 3) + ((quad & 1) << 2);
            *(uint2*)(Plw + pidx) = uu;
        }
        asm volatile("s_waitcnt lgkmcnt(0)" ::: "memory");
        short8 pf0 = *(const short8*)(Plw + col * 64 + ((quad ^ sw) << 3));
        short8 pf1 = *(const short8*)(Plw + col * 64 + (((quad + 4) ^ sw) << 3));
        // O^T += V^T . P^T
        __builtin_amdgcn_s_setprio(1);
        #pragma unroll
        for (int mt = 0; mt < 4; ++mt) {
            const unsigned short* rowp = &Vl[cur][(col + 16 * mt) * 64];
            short8 a0 = *(const short8*)(rowp + i0);
            O[mt] = __builtin_amdgcn_mfma_f32_16x16x32_bf16(a0, pf0, O[mt], 0, 0, 0);
            short8 a1 = *(const short8*)(rowp + i1);
            O[mt] = __builtin_amdgcn_mfma_f32_16x16x32_bf16(a1, pf1, O[mt], 0, 0, 0);
        }
        __builtin_amdgcn_s_setprio(0);
    }
    // single cross-lane reduce of l (keys split across quads at same col)
    l += __shfl_xor(l, 16, 64);
    l += __shfl_xor(l, 32, 64);
    float rl = 1.0f / l;
    unsigned short* yp = y + ((size_t)b * Nn + qrow) * Ee + h * Dd;
    #pragma unroll
    for (int mt = 0; mt < 4; ++mt) {
        f32x4 o = O[mt] * rl;
        uint2 uu;
        uu.x = pk_bf16(o[0], o[1]);
        uu.y = pk_bf16(o[2], o[3]);
        *(uint2*)(yp + mt * 16 + quad * 4) = uu;
    }
}

// MFMA NT GEMM: out[m][e] = sum_f y[m][f]*W[e][f] + bias[e]
// 64(m) x 128(e) tile, BK=64, double-buffered async-DMA staging (one barrier
// per k-step), XOR swizzle, grid (6,128) = 768 blocks (3/CU resident).
// Wave wv owns e-range wv*32: acc[mi 0..3][ni 0..1].
__global__ __launch_bounds__(256) void proj_kernel(
    const unsigned short* __restrict__ y, const unsigned short* __restrict__ w,
    const float* __restrict__ bias, float* __restrict__ out)
{
    __shared__ __align__(16) unsigned short Al[2][64 * 64];
    __shared__ __align__(16) unsigned short Bl[2][128 * 64];
    int t = threadIdx.x;
    int wv = t >> 6, lane = t & 63;
    int quad = lane >> 4, col = lane & 15;
    int e0 = blockIdx.x * 128, m0 = blockIdx.y * 64;
    int l8 = lane >> 3, c8 = lane & 7;
    int g8 = (c8 ^ l8) * 8;
    f32x4 acc[4][2];
    #pragma unroll
    for (int i = 0; i < 4; ++i)
        #pragma unroll
        for (int j = 0; j < 2; ++j) acc[i][j] = (f32x4){0.f, 0.f, 0.f, 0.f};

    // prologue: stage k0 = 0 into buffer 0
    #pragma unroll
    for (int c = 0; c < 2; ++c) {
        int r = wv * 16 + c * 8 + l8;
        gload16(y + (size_t)(m0 + r) * Ee + g8, &Al[0][(wv * 16 + c * 8) * 64]);
    }
    #pragma unroll
    for (int c = 0; c < 4; ++c) {
        int r = wv * 32 + c * 8 + l8;
        gload16(w + (size_t)(e0 + r) * Ee + g8, &Bl[0][(wv * 32 + c * 8) * 64]);
    }

    for (int ks = 0; ks < Ee / 64; ++ks) {
        int cur = ks & 1;
        asm volatile("s_waitcnt vmcnt(0)" ::: "memory");
        __syncthreads();
        if (ks + 1 < Ee / 64) {            // prefetch next k-tile
            int k0n = (ks + 1) * 64;
            #pragma unroll
            for (int c = 0; c < 2; ++c) {
                int r = wv * 16 + c * 8 + l8;
                gload16(y + (size_t)(m0 + r) * Ee + k0n + g8,
                        &Al[cur ^ 1][(wv * 16 + c * 8) * 64]);
            }
            #pragma unroll
            for (int c = 0; c < 4; ++c) {
                int r = wv * 32 + c * 8 + l8;
                gload16(w + (size_t)(e0 + r) * Ee + k0n + g8,
                        &Bl[cur ^ 1][(wv * 32 + c * 8) * 64]);
            }
        }
        __builtin_amdgcn_s_setprio(1);
        #pragma unroll
        for (int kc = 0; kc < 2; ++kc) {
            short8 a[4], bb[2];
            #pragma unroll
            for (int mi = 0; mi < 4; ++mi) {
                int row = mi * 16 + col;
                int sl = ((kc * 4 + quad) ^ (row & 7)) * 8;
                a[mi] = *(const short8*)(&Al[cur][row * 64 + sl]);
            }
            #pragma unroll
            for (int ni = 0; ni < 2; ++ni) {
                int row = wv * 32 + ni * 16 + col;
                int sl = ((kc * 4 + quad) ^ (row & 7)) * 8;
                bb[ni] = *(const short8*)(&Bl[cur][row * 64 + sl]);
            }
            #pragma unroll
            for (int mi = 0; mi < 4; ++mi)
                #pragma unroll
                for (int ni = 0; ni < 2; ++ni)
                    acc[mi][ni] = __builtin_amdgcn_mfma_f32_16x16x32_bf16(a[mi], bb[ni], acc[mi][ni], 0, 0, 0);
        }
        __builtin_amdgcn_s_setprio(0);
    }
    // C layout: e-col = col, m-row = quad*4 + r
    #pragma unroll
    for (int ni = 0; ni < 2; ++ni) {
        int e = e0 + wv * 32 + ni * 16 + col;
        float be = bias[e];
        #pragma unroll
        for (int mi = 0; mi < 4; ++mi) {
            int mrow = m0 + mi * 16 + quad * 4;
            #pragma unroll
            for (int r = 0; r < 4; ++r)
                out[(size_t)(mrow + r) * Ee + e] = acc[mi][ni][r] + be;
        }
    }
}

extern "C" void kernel_launch(void* const* d_in, const int* in_sizes, int n_in,
                              void* d_out, int out_size, void* d_ws, size_t ws_size,
                              hipStream_t stream) {
    const float* q      = (const float*)d_in[0];
    const float* k      = (const float*)d_in[1];
    const float* v      = (const float*)d_in[2];
    const float* qscale = (const float*)d_in[3];
    const float* kscale = (const float*)d_in[4];
    const float* projw  = (const float*)d_in[5];
    const float* projb  = (const float*)d_in[6];
    float* out = (float*)d_out;

    char* base = (char*)d_ws;
    float* ctab  = (float*)(base);
    float* stab  = (float*)(base + 131072);
    float* sctab = (float*)(base + 262144);
    unsigned short* qn   = (unsigned short*)(base + 393216);
    unsigned short* kn   = (unsigned short*)(base + 12976128);
    unsigned short* vt   = (unsigned short*)(base + 25559040);
    unsigned short* yatt = (unsigned short*)(base + 38141952);
    unsigned short* wb   = (unsigned short*)(base + 50724864);

    misc_kernel<<<128 + (Ee * Ee / 4) / 256, 256, 0, stream>>>(
        ctab, stab, sctab, projw, wb);
    prep_kernel<<<(Bb * Hh * Nn) / 4, 256, 0, stream>>>(
        q, k, qscale, kscale, ctab, stab, sctab, qn, kn);
    vt_kernel<<<Bb * Hh * 32, 256, 0, stream>>>(v, vt);

    dim3 agrid(Bb * Hh, NTQ);                            // (48, 32): bh -> XCD
    attn_kernel<<<agrid, 256, 0, stream>>>(qn, kn, vt, yatt);

    dim3 ggrid(Ee / 128, (Bb * Nn) / 64);                // (6, 128)
    proj_kernel<<<ggrid, 256, 0, stream>>>(yatt, wb, projb, out);
}

// Round 3
// 213.505 us; speedup vs baseline: 1.0884x; 1.0309x over previous
//
#include <hip/hip_runtime.h>
#include <hip/hip_bf16.h>
#include <math.h>

#define Bb 4
#define Nn 2048
#define Ee 768
#define Hh 12
#define Dd 64
#define RD 32
#define EPSf 1e-6f
#define NEG_BIG -3.0e38f
#define NTQB 16   // number of 128-row q blocks per (b,h)

typedef __attribute__((ext_vector_type(8))) short short8;
typedef __attribute__((ext_vector_type(4))) float f32x4;

__device__ inline float wave_reduce_sum(float v) {
    #pragma unroll
    for (int m = 1; m < 64; m <<= 1) v += __shfl_xor(v, m, 64);
    return v;
}

// scalar round-to-nearest-even fp32 -> bf16 bits (cheap kernels only)
__device__ inline unsigned f2bf(float x) {
    union { float f; unsigned u; } c; c.f = x;
    unsigned r = c.u + 0x7FFFu + ((c.u >> 16) & 1u);
    return r >> 16;
}

// packed fp32x2 -> bf16x2 (v_cvt_pk_bf16_f32)
__device__ inline unsigned pk_bf16(float a, float b) {
    union { __hip_bfloat162 h; unsigned u; } c;
    c.h = __float22bfloat162_rn(float2{a, b});
    return c.u;
}

// async global->LDS DMA, 16 B per lane; lds dest = uniform base + lane*16
__device__ inline void gload16(const void* g, void* l) {
    __builtin_amdgcn_global_load_lds(
        (const __attribute__((address_space(1))) void*)g,
        (__attribute__((address_space(3))) void*)l,
        16, 0, 0);
}

// Fused: rope/xpos tables (fp64) + W fp32->bf16 conversion.
// Blocks [0, 128): tables; blocks [128, 128+576): W convert.
__global__ __launch_bounds__(256) void misc_kernel(
    float* __restrict__ ctab, float* __restrict__ stab, float* __restrict__ sctab,
    const float* __restrict__ w, unsigned short* __restrict__ wb)
{
    int bx = blockIdx.x;
    if (bx < 128) {
        int idx = bx * 256 + threadIdx.x;
        int n = idx >> 4, i = idx & 15;
        double inv_freq = pow(10000.0, -(double)(2 * i) / (double)RD);
        double ang = (double)n * inv_freq;
        ctab[idx] = (float)cos(ang);
        stab[idx] = (float)sin(ang);
        double base = (2.0 * (double)i + 0.4 * (double)RD) / (1.4 * (double)RD);
        double pw = ((double)n - (double)(Nn / 2)) / 512.0;
        sctab[idx] = (float)pow(base, pw);
    } else {
        int idx = (bx - 128) * 256 + threadIdx.x;   // one float4 each
        float4 v = ((const float4*)w)[idx];
        uint2 uu;
        uu.x = pk_bf16(v.x, v.y);
        uu.y = pk_bf16(v.z, v.w);
        *(uint2*)(wb + (size_t)idx * 4) = uu;
    }
}

// One wave per (b,h,n): RMS-norm + xPos rope; writes bf16 (B,H,N,D).
// 1/sqrt(D) * log2(e) folded into q so softmax uses exp2.
__global__ __launch_bounds__(256) void prep_kernel(
    const float* __restrict__ q, const float* __restrict__ k,
    const float* __restrict__ qscale, const float* __restrict__ kscale,
    const float* __restrict__ ctab, const float* __restrict__ stab,
    const float* __restrict__ sctab,
    unsigned short* __restrict__ qn, unsigned short* __restrict__ kn)
{
    int wave = blockIdx.x * 4 + (threadIdx.x >> 6);
    int lane = threadIdx.x & 63;
    int n  = wave % Nn;
    int bh = wave / Nn;
    int h  = bh % Hh;
    int b  = bh / Hh;
    int gidx = (b * Nn + n) * Ee + h * Dd + lane;
    float xq = q[gidx], xk = k[gidx];
    float msq = wave_reduce_sum(xq * xq) * (1.0f / 64.0f);
    float msk = wave_reduce_sum(xk * xk) * (1.0f / 64.0f);
    float xqn = xq * qscale[lane] * rsqrtf(msq + EPSf);
    float xkn = xk * kscale[lane] * rsqrtf(msk + EPSf);
    float pq = __shfl_xor(xqn, 1, 64);
    float pk = __shfl_xor(xkn, 1, 64);
    float oq = xqn, ok = xkn;
    if (lane < RD) {
        int i = lane >> 1;
        float c  = ctab[n * 16 + i];
        float s  = stab[n * 16 + i];
        float sc = sctab[n * 16 + i];
        float rq = (lane & 1) ? pq : -pq;
        float rk = (lane & 1) ? pk : -pk;
        oq = (xqn * c + rq * s) * sc;
        ok = (xkn * c + rk * s) / sc;
    }
    oq *= 0.125f * 1.44269504088896f;   // 1/sqrt(D) * log2(e)
    size_t oidx = (size_t)bh * (Nn * Dd) + (size_t)n * Dd + lane;
    qn[oidx] = (unsigned short)f2bf(oq);
    kn[oidx] = (unsigned short)f2bf(ok);
}

// Transpose V: (B,N,E) fp32 -> (B,H,D,N) bf16
__global__ __launch_bounds__(256) void vt_kernel(
    const float* __restrict__ v, unsigned short* __restrict__ vt)
{
    __shared__ float Vl[64 * 65];
    int t = threadIdx.x;
    int bh = blockIdx.x >> 5;
    int n0 = (blockIdx.x & 31) * 64;
    int b = bh / Hh, h = bh % Hh;
    const float4* v4 = (const float4*)v;
    #pragma unroll
    for (int c = 0; c < 4; ++c) {
        int idx = t + c * 256;
        int n = idx >> 4, d4 = idx & 15;
        float4 vv = v4[(size_t)(b * Nn + n0 + n) * (Ee / 4) + h * 16 + d4];
        int la = n * 65 + d4 * 4;
        Vl[la] = vv.x; Vl[la + 1] = vv.y; Vl[la + 2] = vv.z; Vl[la + 3] = vv.w;
    }
    __syncthreads();
    #pragma unroll
    for (int c = 0; c < 16; ++c) {
        int linear = t + c * 256;
        int d = linear >> 6, n = linear & 63;
        vt[((size_t)bh * Dd + d) * Nn + n0 + n] = (unsigned short)f2bf(Vl[n * 65 + d]);
    }
}

// MFMA flash attention (causal), NO-MAX softmax, WIDE q per wave.
// QBLK=128 per block: 4 waves x 32 q (two 16-q groups A/B per wave).
// K/V LDS fragments a0/a1 are read ONCE and feed both groups' MFMAs
// -> LDS read traffic per softmax element drops ~45%.
// Row-sum l computed by MFMA with all-ones A operand (no scalar adds).
// Double-buffered K/V staging, one barrier per tile, heavy-first dispatch.
// LDS = 16K (K x2) + 16K (V x2) + 16K (P) = 49152 B -> 3 blocks/CU;
// grid (48,16) = 768 blocks = exactly 3/CU: whole grid co-resident.
__global__ __launch_bounds__(256, 3) void attn_kernel(
    const unsigned short* __restrict__ qn, const unsigned short* __restrict__ kn,
    const unsigned short* __restrict__ vt, unsigned short* __restrict__ y)
{
    __shared__ __align__(16) unsigned short Kl[2][64 * 64];
    __shared__ __align__(16) unsigned short Vl[2][64 * 64];    // V^T: [dim][key]
    __shared__ __align__(16) unsigned short Pl[8][16 * 64];    // per (wave,group)
    int t = threadIdx.x;
    int w = t >> 6, lane = t & 63;
    int quad = lane >> 4, col = lane & 15;
    int bh = blockIdx.x;
    int b = bh / Hh, h = bh % Hh;
    int qt = (NTQB - 1) - (int)blockIdx.y;     // heavy blocks dispatched first
    const unsigned short* kbh = kn + (size_t)bh * Nn * Dd;
    const unsigned short* vbh = vt + (size_t)bh * Dd * Nn;
    unsigned short* PlA = Pl[w * 2];
    unsigned short* PlB = Pl[w * 2 + 1];

    int l8 = lane >> 3, c8 = lane & 7;
    int g8 = (c8 ^ l8) * 8;                 // element offset of source chunk
    int sw = col & 7;
    int i0 = ((quad    ) ^ sw) * 8;         // chunks 0..31
    int i1 = ((quad + 4) ^ sw) * 8;         // chunks 32..63

    int q0 = qt * 128;
    int qgA = q0 + w * 32;                  // group A min row (wave-uniform)
    int qArow = qgA + col;
    int qBrow = qArow + 16;
    const unsigned short* qpA = qn + ((size_t)bh * Nn + qArow) * Dd;
    short8 qf0A = *(const short8*)(qpA + quad * 8);
    short8 qf1A = *(const short8*)(qpA + 32 + quad * 8);
    const unsigned short* qpB = qpA + 16 * Dd;
    short8 qf0B = *(const short8*)(qpB + quad * 8);
    short8 qf1B = *(const short8*)(qpB + 32 + quad * 8);

    short8 ones;                            // bf16 1.0 in all 8 slots
    #pragma unroll
    for (int i = 0; i < 8; ++i) ones[i] = (short)0x3F80;

    const f32x4 Zc = (f32x4){0.f, 0.f, 0.f, 0.f};
    f32x4 OA[4], OB[4], LsA = Zc, LsB = Zc;
    #pragma unroll
    for (int i = 0; i < 4; ++i) { OA[i] = Zc; OB[i] = Zc; }
    int ntiles = 2 * qt + 2;

    // prologue: stage tile 0 into buffer 0
    #pragma unroll
    for (int c = 0; c < 2; ++c) {
        int r = w * 16 + c * 8 + l8;
        int dstbase = (w * 16 + c * 8) * 64;
        gload16(kbh + ((size_t)r << 6) + g8, &Kl[0][dstbase]);
        gload16(vbh + (size_t)r * Nn + g8, &Vl[0][dstbase]);
    }

    for (int tile = 0; tile < ntiles; ++tile) {
        int cur = tile & 1;
        int j0 = tile * 64;
        // drain my DMA for buffer[cur]; barrier makes all waves' stages
        // visible AND guarantees buffer[cur^1] readers (tile-1) are done.
        asm volatile("s_waitcnt vmcnt(0)" ::: "memory");
        __syncthreads();
        if (tile + 1 < ntiles) {           // prefetch next tile -> other buffer
            int j0n = j0 + 64;
            #pragma unroll
            for (int c = 0; c < 2; ++c) {
                int r = w * 16 + c * 8 + l8;
                int dstbase = (w * 16 + c * 8) * 64;
                gload16(kbh + ((size_t)(j0n + r) << 6) + g8, &Kl[cur ^ 1][dstbase]);
                gload16(vbh + (size_t)r * Nn + j0n + g8, &Vl[cur ^ 1][dstbase]);
            }
        }
        // last tile (keys q0+64..q0+127): waves 0,1 (rows < q0+64) fully masked
        bool act = (tile != ntiles - 1) || (w >= 2);
        if (!act) continue;                // still hit next iteration's barrier

        // S^T = K . Q^T for both q-groups; K fragments read once, used twice.
        f32x4 SA[4], SB[4];
        __builtin_amdgcn_s_setprio(1);
        #pragma unroll
        for (int mt = 0; mt < 4; ++mt) {
            const unsigned short* rowp = &Kl[cur][(col + 16 * mt) * 64];
            short8 a0 = *(const short8*)(rowp + i0);
            short8 a1 = *(const short8*)(rowp + i1);
            SA[mt] = __builtin_amdgcn_mfma_f32_16x16x32_bf16(a0, qf0A, Zc, 0, 0, 0);
            SA[mt] = __builtin_amdgcn_mfma_f32_16x16x32_bf16(a1, qf1A, SA[mt], 0, 0, 0);
            SB[mt] = __builtin_amdgcn_mfma_f32_16x16x32_bf16(a0, qf0B, Zc, 0, 0, 0);
            SB[mt] = __builtin_amdgcn_mfma_f32_16x16x32_bf16(a1, qf1B, SB[mt], 0, 0, 0);
        }
        __builtin_amdgcn_s_setprio(0);
        if (j0 + 63 > qgA) {               // diagonal for group A
            #pragma unroll
            for (int mt = 0; mt < 4; ++mt)
                #pragma unroll
                for (int r = 0; r < 4; ++r) {
                    int key = j0 + mt * 16 + quad * 4 + r;
                    if (key > qArow) SA[mt][r] = NEG_BIG;
                }
        }
        if (j0 + 63 > qgA + 16) {          // diagonal for group B
            #pragma unroll
            for (int mt = 0; mt < 4; ++mt)
                #pragma unroll
                for (int r = 0; r < 4; ++r) {
                    int key = j0 + mt * 16 + quad * 4 + r;
                    if (key > qBrow) SB[mt][r] = NEG_BIG;
                }
        }
        // no-max softmax: P = exp2(S); pack to per-group LDS scratch
        #pragma unroll
        for (int mt = 0; mt < 4; ++mt) {
            uint2 ua, ub;
            ua.x = pk_bf16(exp2f(SA[mt][0]), exp2f(SA[mt][1]));
            ua.y = pk_bf16(exp2f(SA[mt][2]), exp2f(SA[mt][3]));
            ub.x = pk_bf16(exp2f(SB[mt][0]), exp2f(SB[mt][1]));
            ub.y = pk_bf16(exp2f(SB[mt][2]), exp2f(SB[mt][3]));
            int pidx = col * 64 + (((2 * mt + (quad >> 1)) ^ sw) << 3) + ((quad & 1) << 2);
            *(uint2*)(PlA + pidx) = ua;
            *(uint2*)(PlB + pidx) = ub;
        }
        asm volatile("s_waitcnt lgkmcnt(0)" ::: "memory");
        int pr0 = col * 64 + ((quad ^ sw) << 3);
        int pr1 = col * 64 + (((quad + 4) ^ sw) << 3);
        short8 pfA0 = *(const short8*)(PlA + pr0);
        short8 pfA1 = *(const short8*)(PlA + pr1);
        short8 pfB0 = *(const short8*)(PlB + pr0);
        short8 pfB1 = *(const short8*)(PlB + pr1);
        // row sums via MFMA with all-ones A: every lane gets l for q=col
        LsA = __builtin_amdgcn_mfma_f32_16x16x32_bf16(ones, pfA0, LsA, 0, 0, 0);
        LsA = __builtin_amdgcn_mfma_f32_16x16x32_bf16(ones, pfA1, LsA, 0, 0, 0);
        LsB = __builtin_amdgcn_mfma_f32_16x16x32_bf16(ones, pfB0, LsB, 0, 0, 0);
        LsB = __builtin_amdgcn_mfma_f32_16x16x32_bf16(ones, pfB1, LsB, 0, 0, 0);
        // O^T += V^T . P^T; V fragments read once, used twice.
        __builtin_amdgcn_s_setprio(1);
        #pragma unroll
        for (int mt = 0; mt < 4; ++mt) {
            const unsigned short* rowp = &Vl[cur][(col + 16 * mt) * 64];
            short8 a0 = *(const short8*)(rowp + i0);
            short8 a1 = *(const short8*)(rowp + i1);
            OA[mt] = __builtin_amdgcn_mfma_f32_16x16x32_bf16(a0, pfA0, OA[mt], 0, 0, 0);
            OA[mt] = __builtin_amdgcn_mfma_f32_16x16x32_bf16(a1, pfA1, OA[mt], 0, 0, 0);
            OB[mt] = __builtin_amdgcn_mfma_f32_16x16x32_bf16(a0, pfB0, OB[mt], 0, 0, 0);
            OB[mt] = __builtin_amdgcn_mfma_f32_16x16x32_bf16(a1, pfB1, OB[mt], 0, 0, 0);
        }
        __builtin_amdgcn_s_setprio(0);
    }
    float rlA = 1.0f / LsA[0];
    float rlB = 1.0f / LsB[0];
    unsigned short* ypA = y + ((size_t)(b * Nn + qArow)) * Ee + h * Dd;
    unsigned short* ypB = y + ((size_t)(b * Nn + qBrow)) * Ee + h * Dd;
    #pragma unroll
    for (int mt = 0; mt < 4; ++mt) {
        f32x4 oa = OA[mt] * rlA;
        f32x4 ob = OB[mt] * rlB;
        uint2 ua, ub;
        ua.x = pk_bf16(oa[0], oa[1]);
        ua.y = pk_bf16(oa[2], oa[3]);
        ub.x = pk_bf16(ob[0], ob[1]);
        ub.y = pk_bf16(ob[2], ob[3]);
        *(uint2*)(ypA + mt * 16 + quad * 4) = ua;
        *(uint2*)(ypB + mt * 16 + quad * 4) = ub;
    }
}

// MFMA NT GEMM: out[m][e] = sum_f y[m][f]*W[e][f] + bias[e]
// 64(m) x 128(e) tile, BK=64, double-buffered async-DMA staging (one barrier
// per k-step), XOR swizzle, grid (6,128) = 768 blocks (3/CU resident).
// Wave wv owns e-range wv*32: acc[mi 0..3][ni 0..1].
__global__ __launch_bounds__(256) void proj_kernel(
    const unsigned short* __restrict__ y, const unsigned short* __restrict__ w,
    const float* __restrict__ bias, float* __restrict__ out)
{
    __shared__ __align__(16) unsigned short Al[2][64 * 64];
    __shared__ __align__(16) unsigned short Bl[2][128 * 64];
    int t = threadIdx.x;
    int wv = t >> 6, lane = t & 63;
    int quad = lane >> 4, col = lane & 15;
    int e0 = blockIdx.x * 128, m0 = blockIdx.y * 64;
    int l8 = lane >> 3, c8 = lane & 7;
    int g8 = (c8 ^ l8) * 8;
    f32x4 acc[4][2];
    #pragma unroll
    for (int i = 0; i < 4; ++i)
        #pragma unroll
        for (int j = 0; j < 2; ++j) acc[i][j] = (f32x4){0.f, 0.f, 0.f, 0.f};

    // prologue: stage k0 = 0 into buffer 0
    #pragma unroll
    for (int c = 0; c < 2; ++c) {
        int r = wv * 16 + c * 8 + l8;
        gload16(y + (size_t)(m0 + r) * Ee + g8, &Al[0][(wv * 16 + c * 8) * 64]);
    }
    #pragma unroll
    for (int c = 0; c < 4; ++c) {
        int r = wv * 32 + c * 8 + l8;
        gload16(w + (size_t)(e0 + r) * Ee + g8, &Bl[0][(wv * 32 + c * 8) * 64]);
    }

    for (int ks = 0; ks < Ee / 64; ++ks) {
        int cur = ks & 1;
        asm volatile("s_waitcnt vmcnt(0)" ::: "memory");
        __syncthreads();
        if (ks + 1 < Ee / 64) {            // prefetch next k-tile
            int k0n = (ks + 1) * 64;
            #pragma unroll
            for (int c = 0; c < 2; ++c) {
                int r = wv * 16 + c * 8 + l8;
                gload16(y + (size_t)(m0 + r) * Ee + k0n + g8,
                        &Al[cur ^ 1][(wv * 16 + c * 8) * 64]);
            }
            #pragma unroll
            for (int c = 0; c < 4; ++c) {
                int r = wv * 32 + c * 8 + l8;
                gload16(w + (size_t)(e0 + r) * Ee + k0n + g8,
                        &Bl[cur ^ 1][(wv * 32 + c * 8) * 64]);
            }
        }
        __builtin_amdgcn_s_setprio(1);
        #pragma unroll
        for (int kc = 0; kc < 2; ++kc) {
            short8 a[4], bb[2];
            #pragma unroll
            for (int mi = 0; mi < 4; ++mi) {
                int row = mi * 16 + col;
                int sl = ((kc * 4 + quad) ^ (row & 7)) * 8;
                a[mi] = *(const short8*)(&Al[cur][row * 64 + sl]);
            }
            #pragma unroll
            for (int ni = 0; ni < 2; ++ni) {
                int row = wv * 32 + ni * 16 + col;
                int sl = ((kc * 4 + quad) ^ (row & 7)) * 8;
                bb[ni] = *(const short8*)(&Bl[cur][row * 64 + sl]);
            }
            #pragma unroll
            for (int mi = 0; mi < 4; ++mi)
                #pragma unroll
                for (int ni = 0; ni < 2; ++ni)
                    acc[mi][ni] = __builtin_amdgcn_mfma_f32_16x16x32_bf16(a[mi], bb[ni], acc[mi][ni], 0, 0, 0);
        }
        __builtin_amdgcn_s_setprio(0);
    }
    // C layout: e-col = col, m-row = quad*4 + r
    #pragma unroll
    for (int ni = 0; ni < 2; ++ni) {
        int e = e0 + wv * 32 + ni * 16 + col;
        float be = bias[e];
        #pragma unroll
        for (int mi = 0; mi < 4; ++mi) {
            int mrow = m0 + mi * 16 + quad * 4;
            #pragma unroll
            for (int r = 0; r < 4; ++r)
                out[(size_t)(mrow + r) * Ee + e] = acc[mi][ni][r] + be;
        }
    }
}

extern "C" void kernel_launch(void* const* d_in, const int* in_sizes, int n_in,
                              void* d_out, int out_size, void* d_ws, size_t ws_size,
                              hipStream_t stream) {
    const float* q      = (const float*)d_in[0];
    const float* k      = (const float*)d_in[1];
    const float* v      = (const float*)d_in[2];
    const float* qscale = (const float*)d_in[3];
    const float* kscale = (const float*)d_in[4];
    const float* projw  = (const float*)d_in[5];
    const float* projb  = (const float*)d_in[6];
    float* out = (float*)d_out;

    char* base = (char*)d_ws;
    float* ctab  = (float*)(base);
    float* stab  = (float*)(base + 131072);
    float* sctab = (float*)(base + 262144);
    unsigned short* qn   = (unsigned short*)(base + 393216);
    unsigned short* kn   = (unsigned short*)(base + 12976128);
    unsigned short* vt   = (unsigned short*)(base + 25559040);
    unsigned short* yatt = (unsigned short*)(base + 38141952);
    unsigned short* wb   = (unsigned short*)(base + 50724864);

    misc_kernel<<<128 + (Ee * Ee / 4) / 256, 256, 0, stream>>>(
        ctab, stab, sctab, projw, wb);
    prep_kernel<<<(Bb * Hh * Nn) / 4, 256, 0, stream>>>(
        q, k, qscale, kscale, ctab, stab, sctab, qn, kn);
    vt_kernel<<<Bb * Hh * 32, 256, 0, stream>>>(v, vt);

    dim3 agrid(Bb * Hh, NTQB);                           // (48, 16): bh -> XCD
    attn_kernel<<<agrid, 256, 0, stream>>>(qn, kn, vt, yatt);

    dim3 ggrid(Ee / 128, (Bb * Nn) / 64);                // (6, 128)
    proj_kernel<<<ggrid, 256, 0, stream>>>(yatt, wb, projb, out);
}